// Round 3
// baseline (375.998 us; speedup 1.0000x reference)
//
#include <hip/hip_runtime.h>
#include <hip/hip_bf16.h>
#include <math.h>

// ---------------------------------------------------------------------------
// GATGNN global attention:  softmax_seg( MLP([x|glbl]) )  on MI355X (gfx950)
// R2: 256x256 tile, 512 thr (8 waves), BK=32, ring-4 LDS (128KB), counted
//     vmcnt(8) pipeline (T3+T4), setprio around MFMA (T5). Fused epilogues.
// ---------------------------------------------------------------------------

#define NSEG 1024

typedef __attribute__((ext_vector_type(8))) short short8;
typedef __attribute__((ext_vector_type(4))) float f32x4;

__device__ __forceinline__ float bf2f(unsigned short u) {
  union { unsigned int i; float f; } c; c.i = ((unsigned int)u) << 16; return c.f;
}
__device__ __forceinline__ unsigned short f2bf(float f) {
  __hip_bfloat16 h = __float2bfloat16(f);
  return *reinterpret_cast<unsigned short*>(&h);
}
__device__ __forceinline__ float softplus_fast(float z) {
  float t = __expf(-fabsf(z));
  return fmaxf(z, 0.f) + __logf(1.f + t);
}

__device__ __forceinline__ void gll16(const unsigned short* g, unsigned short* l) {
  __builtin_amdgcn_global_load_lds(
      (const __attribute__((address_space(1))) void*)g,
      (__attribute__((address_space(3))) void*)l, 16, 0, 0);
}

// ---------------------------------------------------------------------------
// Pack A0 = [x | glbl | zeros] as bf16 [Mp, 640]; pad rows (>=N) zeroed.
// ---------------------------------------------------------------------------
__global__ __launch_bounds__(256) void pack_a0(const float* __restrict__ x,
                                               const float* __restrict__ gx,
                                               unsigned short* __restrict__ A0,
                                               int N, int Mp) {
  int t = blockIdx.x * 256 + threadIdx.x;
  if (t >= Mp * 80) return;
  int row = t / 80, c = t % 80;
  union { unsigned short u[8]; uint4 q; } v;
  if (row >= N) {
#pragma unroll
    for (int j = 0; j < 8; ++j) v.u[j] = 0;
  } else if (c < 64) {
    const float4* p = (const float4*)(x + (size_t)row * 512 + c * 8);
    float4 a = p[0], b = p[1];
    v.u[0] = f2bf(a.x); v.u[1] = f2bf(a.y); v.u[2] = f2bf(a.z); v.u[3] = f2bf(a.w);
    v.u[4] = f2bf(b.x); v.u[5] = f2bf(b.y); v.u[6] = f2bf(b.z); v.u[7] = f2bf(b.w);
  } else {
#pragma unroll
    for (int j = 0; j < 8; ++j) {
      int col = c * 8 + j;
      float f = (col < 620) ? gx[(size_t)row * 108 + (col - 512)] : 0.f;
      v.u[j] = f2bf(f);
    }
  }
  *reinterpret_cast<uint4*>(A0 + (size_t)row * 640 + c * 8) = v.q;
}

// W0 [620,512] f32 -> W0T bf16 [512,640] (transposed, K padded with zeros)
__global__ __launch_bounds__(256) void pack_w0t(const float* __restrict__ W0,
                                                unsigned short* __restrict__ W0T) {
  int t = blockIdx.x * 256 + threadIdx.x;
  if (t >= 512 * 640) return;
  int n = t / 640, k = t % 640;
  float f = (k < 620) ? W0[(size_t)k * 512 + n] : 0.f;
  W0T[t] = f2bf(f);
}

// W1 [512,512] f32 -> W1T bf16 [512,512] (transposed)
__global__ __launch_bounds__(256) void pack_w1t(const float* __restrict__ W1,
                                                unsigned short* __restrict__ W1T) {
  int t = blockIdx.x * 256 + threadIdx.x;
  if (t >= 512 * 512) return;
  int n = t / 512, k = t % 512;
  W1T[t] = f2bf(W1[(size_t)k * 512 + n]);
}

__global__ __launch_bounds__(256) void zero_f32(float* __restrict__ p, int n) {
  int i = blockIdx.x * 256 + threadIdx.x;
  if (i < n) p[i] = 0.f;
}

// ---------------------------------------------------------------------------
// GEMM: Z[M,512] = A[M,K] * BT[512,K]^T + bias; 256x256 block tile, BK=32,
// 8 waves (2x4), 128x64 per wave, mfma(bf,af) (swapped) so each thread holds
// 4 consecutive output columns.
//   Ring-4 LDS double... quad-buffer; stage tile kt+3 while computing kt.
//   Per-iter: vmcnt(8) [tiles kt+1,kt+2 may stay in flight] -> s_barrier ->
//   stage -> ds_read 12 frags -> setprio(1) -> 32 MFMA -> setprio(0).
//   Safety: buf[(kt+3)&3] was last read at iter kt-1 (reads retired before
//   that iter's MFMAs via lgkmcnt); the barrier orders all waves past it.
//   vmcnt in-order retire => tile kt landed for every wave before its reads.
//  FUSE=false: C = bf16(softplus(Z))                      (layer 0 -> H0)
//  FUSE=true : logits[m] += sum_n softplus(Z[m,n])*W2[n]  (layers 1+2 fused)
// ---------------------------------------------------------------------------
template <int K, bool FUSE>
__global__ __launch_bounds__(512, 2) void gemm_bf16(const unsigned short* __restrict__ A,
                                                    const unsigned short* __restrict__ BT,
                                                    const float* __restrict__ bias,
                                                    unsigned short* __restrict__ C,
                                                    const float* __restrict__ W2,
                                                    float* __restrict__ logits) {
  constexpr int KT = K / 32;
  __shared__ unsigned short As[4][256 * 32];  // 64 KiB
  __shared__ unsigned short Bs[4][256 * 32];  // 64 KiB
  const int tid = threadIdx.x;             // 0..511
  const int nt = blockIdx.x & 1;           // 512/256 = 2 col tiles (pairs share A panel -> L2)
  const int mt = blockIdx.x >> 1;
  const int lane = tid & 63;
  const int wid = tid >> 6;                // 0..7
  const int wm = wid >> 2, wn = wid & 3;   // 2 x 4 wave grid: 128 rows x 64 cols each
  const int lm = lane & 15;
  const int rch = lane >> 4;               // k-chunk 0..3 (8 bf16 each)

  const unsigned short* Ag = A + (size_t)mt * 256 * K;
  const unsigned short* Bg = BT + (size_t)nt * 256 * K;

  f32x4 acc[8][4] = {};

  auto stage = [&](int buf, int kb) {
#pragma unroll
    for (int i = 0; i < 2; ++i) {
      int f = i * 512 + tid;
      int row = f >> 2;
      int sc = ((f & 3) ^ ((row >> 1) & 3)) << 3;   // zero-conflict chunk swizzle
      gll16(Ag + (size_t)row * K + kb + sc, &As[buf][f * 8]);
    }
#pragma unroll
    for (int i = 0; i < 2; ++i) {
      int f = i * 512 + tid;
      int row = f >> 2;
      int sc = ((f & 3) ^ ((row >> 1) & 3)) << 3;
      gll16(Bg + (size_t)row * K + kb + sc, &Bs[buf][f * 8]);
    }
  };

  // prologue: prefetch tiles 0,1,2 (KT >= 16 always)
  stage(0, 0);
  stage(1, 32);
  stage(2, 64);

  for (int kt = 0; kt < KT; ++kt) {
    const int cur = kt & 3;
    const int rem = KT - 1 - kt;
    if (rem >= 2)      asm volatile("s_waitcnt vmcnt(8)" ::: "memory");
    else if (rem == 1) asm volatile("s_waitcnt vmcnt(4)" ::: "memory");
    else               asm volatile("s_waitcnt vmcnt(0)" ::: "memory");
    __builtin_amdgcn_s_barrier();
    asm volatile("" ::: "memory");

    if (kt + 3 < KT) stage((kt + 3) & 3, (kt + 3) * 32);

    short8 af[8], bfr[4];
#pragma unroll
    for (int mi = 0; mi < 8; ++mi) {
      int row = wm * 128 + mi * 16 + lm;
      af[mi] = *reinterpret_cast<const short8*>(
          &As[cur][row * 32 + ((rch ^ ((row >> 1) & 3)) << 3)]);
    }
#pragma unroll
    for (int ni = 0; ni < 4; ++ni) {
      int row = wn * 64 + ni * 16 + lm;
      bfr[ni] = *reinterpret_cast<const short8*>(
          &Bs[cur][row * 32 + ((rch ^ ((row >> 1) & 3)) << 3)]);
    }
    __builtin_amdgcn_s_setprio(1);
#pragma unroll
    for (int mi = 0; mi < 8; ++mi)
#pragma unroll
      for (int ni = 0; ni < 4; ++ni)
        acc[mi][ni] = __builtin_amdgcn_mfma_f32_16x16x32_bf16(bfr[ni], af[mi], acc[mi][ni], 0, 0, 0);
    __builtin_amdgcn_s_setprio(0);
  }

  // Transposed D layout: thread holds C[m][n0..n0+3]
  //   m  = mt*256 + wm*128 + mi*16 + (lane&15)
  //   n0 = nt*256 + wn*64  + ni*16 + (lane>>4)*4
#pragma unroll
  for (int mi = 0; mi < 8; ++mi) {
    const int m = mt * 256 + wm * 128 + mi * 16 + lm;
    float part = 0.f;
#pragma unroll
    for (int ni = 0; ni < 4; ++ni) {
      const int n0 = nt * 256 + wn * 64 + ni * 16 + (rch << 2);
      const f32x4 bb = *reinterpret_cast<const f32x4*>(bias + n0);
      f32x4 v = acc[mi][ni];
      if constexpr (!FUSE) {
        union { unsigned short u[4]; uint2 q; } o;
#pragma unroll
        for (int r = 0; r < 4; ++r) o.u[r] = f2bf(softplus_fast(v[r] + bb[r]));
        *reinterpret_cast<uint2*>(C + (size_t)m * 512 + n0) = o.q;
      } else {
        const f32x4 wv = *reinterpret_cast<const f32x4*>(W2 + n0);
#pragma unroll
        for (int r = 0; r < 4; ++r) part += softplus_fast(v[r] + bb[r]) * wv[r];
      }
    }
    if constexpr (FUSE) {
      part += __shfl_xor(part, 16);
      part += __shfl_xor(part, 32);
      if (lane < 16) atomicAdd(logits + m, part);
    }
  }
}

// ---------------------------------------------------------------------------
// Per-segment softmax: one block per segment; batch is sorted -> binary search
// (b2 omitted: softmax is shift-invariant.)
// ---------------------------------------------------------------------------
__global__ __launch_bounds__(256) void segsoftmax(const float* __restrict__ logits,
                                                  const int* __restrict__ batch,
                                                  float* __restrict__ out, int N) {
  const int g = blockIdx.x;
  const int tid = threadIdx.x;
  int lo = 0, hi = N;
  while (lo < hi) { int mid = (lo + hi) >> 1; if (batch[mid] < g) lo = mid + 1; else hi = mid; }
  const int beg = lo;
  hi = N;
  while (lo < hi) { int mid = (lo + hi) >> 1; if (batch[mid] < g + 1) lo = mid + 1; else hi = mid; }
  const int end = lo;
  if (beg >= end) return;

  __shared__ float sh[4];
  float m = -INFINITY;
  for (int i = beg + tid; i < end; i += 256) m = fmaxf(m, logits[i]);
#pragma unroll
  for (int o = 32; o; o >>= 1) m = fmaxf(m, __shfl_down(m, o));
  if ((tid & 63) == 0) sh[tid >> 6] = m;
  __syncthreads();
  m = fmaxf(fmaxf(sh[0], sh[1]), fmaxf(sh[2], sh[3]));
  __syncthreads();

  float s = 0.f;
  for (int i = beg + tid; i < end; i += 256) s += expf(logits[i] - m);
#pragma unroll
  for (int o = 32; o; o >>= 1) s += __shfl_down(s, o);
  if ((tid & 63) == 0) sh[tid >> 6] = s;
  __syncthreads();
  s = sh[0] + sh[1] + sh[2] + sh[3];

  const float inv = 1.f / (s + 1e-16f);
  for (int i = beg + tid; i < end; i += 256) out[i] = expf(logits[i] - m) * inv;
}

// ---------------------------------------------------------------------------
extern "C" void kernel_launch(void* const* d_in, const int* in_sizes, int n_in,
                              void* d_out, int out_size, void* d_ws, size_t ws_size,
                              hipStream_t stream) {
  const float* x = (const float*)d_in[0];
  const int* batch = (const int*)d_in[1];
  const float* gx = (const float*)d_in[2];
  const float* W0 = (const float*)d_in[3];
  const float* b0 = (const float*)d_in[4];
  const float* W1 = (const float*)d_in[5];
  const float* b1 = (const float*)d_in[6];
  const float* W2 = (const float*)d_in[7];
  float* out = (float*)d_out;

  const int N = in_sizes[1];                 // 100000
  const int Mp = ((N + 255) / 256) * 256;    // 100096 (=256*391)
  const int Mtiles = Mp / 256;

  auto align256 = [](size_t v) { return (v + 255) & ~(size_t)255; };
  char* ws = (char*)d_ws;
  size_t off = 0;
  unsigned short* A0 = (unsigned short*)(ws + off);  off = align256(off + (size_t)Mp * 640 * 2);
  unsigned short* W0T = (unsigned short*)(ws + off); off = align256(off + (size_t)512 * 640 * 2);
  unsigned short* W1T = (unsigned short*)(ws + off); off = align256(off + (size_t)512 * 512 * 2);
  unsigned short* H0 = (unsigned short*)(ws + off);  off = align256(off + (size_t)Mp * 512 * 2);
  float* logits = (float*)(ws + off);                off = align256(off + (size_t)Mp * 4);
  (void)ws_size; (void)n_in; (void)out_size;

  pack_w0t<<<(512 * 640 + 255) / 256, 256, 0, stream>>>(W0, W0T);
  pack_w1t<<<(512 * 512 + 255) / 256, 256, 0, stream>>>(W1, W1T);
  pack_a0<<<(Mp * 80 + 255) / 256, 256, 0, stream>>>(x, gx, A0, N, Mp);
  zero_f32<<<(Mp + 255) / 256, 256, 0, stream>>>(logits, Mp);

  gemm_bf16<640, false><<<Mtiles * 2, 512, 0, stream>>>(A0, W0T, b0, H0, nullptr, nullptr);
  gemm_bf16<512, true><<<Mtiles * 2, 512, 0, stream>>>(H0, W1T, b1, nullptr, W2, logits);

  segsoftmax<<<NSEG, 256, 0, stream>>>(logits, batch, out, N);
}

// Round 4
// 315.086 us; speedup vs baseline: 1.1933x; 1.1933x over previous
//
#include <hip/hip_runtime.h>
#include <hip/hip_bf16.h>
#include <math.h>

// ---------------------------------------------------------------------------
// GATGNN global attention:  softmax_seg( MLP([x|glbl]) )  on MI355X (gfx950)
// R3: pack_a0 fused into GEMM0 (fp32->bf16 reg-staging), 128x128 tiles,
//     4 waves, BK=32, 32KB LDS -> 3 blocks/CU (m97-proven TLP), XCD swizzle.
// ---------------------------------------------------------------------------

#define NSEG 1024

typedef __attribute__((ext_vector_type(8))) short short8;
typedef __attribute__((ext_vector_type(4))) float f32x4;

__device__ __forceinline__ unsigned short f2bf(float f) {
  __hip_bfloat16 h = __float2bfloat16(f);
  return *reinterpret_cast<unsigned short*>(&h);
}
__device__ __forceinline__ float softplus_fast(float z) {
  float t = __expf(-fabsf(z));
  return fmaxf(z, 0.f) + __logf(1.f + t);
}
__device__ __forceinline__ void gll16(const unsigned short* g, unsigned short* l) {
  __builtin_amdgcn_global_load_lds(
      (const __attribute__((address_space(1))) void*)g,
      (__attribute__((address_space(3))) void*)l, 16, 0, 0);
}
// m204 bijective XCD-chunked swizzle: maps bid -> L so each XCD owns a
// contiguous L-range (nt-quads of one mt land on one XCD's L2).
__device__ __forceinline__ int xcd_swz(int bid, int nwg) {
  int q = nwg >> 3, r = nwg & 7, x = bid & 7, i = bid >> 3;
  return (x < r ? x * (q + 1) : r * (q + 1) + (x - r) * q) + i;
}

// ---------------------------------------------------------------------------
// prep: W0 [620,512] -> W0T bf16 [512,640] (K-pad 0), W1 -> W1T [512,512],
//       zero logits.  One launch.
// ---------------------------------------------------------------------------
__global__ __launch_bounds__(256) void prep(const float* __restrict__ W0,
                                            const float* __restrict__ W1,
                                            unsigned short* __restrict__ W0T,
                                            unsigned short* __restrict__ W1T,
                                            float* __restrict__ logits, int Mp) {
  int t = blockIdx.x * 256 + threadIdx.x;
  if (t < 512 * 640) {
    int n = t / 640, k = t % 640;
    W0T[t] = f2bf(k < 620 ? W0[(size_t)k * 512 + n] : 0.f);
    return;
  }
  t -= 512 * 640;
  if (t < 512 * 512) {
    int n = t / 512, k = t % 512;
    W1T[t] = f2bf(W1[(size_t)k * 512 + n]);
    return;
  }
  t -= 512 * 512;
  if (t < Mp) logits[t] = 0.f;
}

// ---------------------------------------------------------------------------
// GEMM0: H0 = bf16(softplus([x|gx|0] * W0T^T + b0)).  128x128 tile, BK=32,
// 4 waves (2x2), 64x64/wave.  A staged from fp32 global via reg-cvt +
// XOR-swizzled ds_write (issue-early/write-late); W via global_load_lds with
// pre-swizzled source.  LDS 32KB, 3 blocks/CU.
// LDS convention: chunk c (8 bf16) of local row r lives at slot c^((r>>1)&3).
// ---------------------------------------------------------------------------
__global__ __launch_bounds__(256, 3) void gemm0(const float* __restrict__ x,
                                                const float* __restrict__ gx,
                                                const unsigned short* __restrict__ W0T,
                                                const float* __restrict__ b0,
                                                unsigned short* __restrict__ H0,
                                                int N, int nwg) {
  constexpr int K = 640, KT = 20;
  __shared__ unsigned short As[2][128 * 32];
  __shared__ unsigned short Ws[2][128 * 32];
  const int L = xcd_swz(blockIdx.x, nwg);
  const int nt = L & 3, mt = L >> 2;
  const int tid = threadIdx.x, lane = tid & 63, wid = tid >> 6;
  const int wm = wid >> 1, wn = wid & 1, lm = lane & 15, rch = lane >> 4;

  // A-staging assignment: thread t -> local row t>>1, col-half (t&1)*16
  const int arow_l = tid >> 1, ah = tid & 1;
  const int arow_g = mt * 128 + arow_l;
  const int ap = (arow_l >> 1) & 3;
  const bool avalid = arow_g < N;
  const unsigned short* Wg = W0T + (size_t)(nt * 128) * K;

  f32x4 acc[4][4] = {};
  float4 va[4];  // 16 fp32 staged for next k-tile (static-indexed)

  auto loadA = [&](int kt) {
    const int c0 = kt * 32 + ah * 16;
    if (kt < 16) {
      if (avalid) {
        const float4* p = (const float4*)(x + (size_t)arow_g * 512 + c0);
#pragma unroll
        for (int j = 0; j < 4; ++j) va[j] = p[j];
      } else {
#pragma unroll
        for (int j = 0; j < 4; ++j) va[j] = float4{0.f, 0.f, 0.f, 0.f};
      }
    } else {
      const int g0 = c0 - 512;
      float tmp[16];
#pragma unroll
      for (int j = 0; j < 16; ++j) {
        int col = g0 + j;
        tmp[j] = (avalid && col < 108) ? gx[(size_t)arow_g * 108 + col] : 0.f;
      }
#pragma unroll
      for (int j = 0; j < 4; ++j)
        va[j] = float4{tmp[4 * j], tmp[4 * j + 1], tmp[4 * j + 2], tmp[4 * j + 3]};
    }
  };
  auto writeA = [&](int buf) {
    union { unsigned short u[8]; uint4 qv; } w0, w1;
    w0.u[0] = f2bf(va[0].x); w0.u[1] = f2bf(va[0].y); w0.u[2] = f2bf(va[0].z); w0.u[3] = f2bf(va[0].w);
    w0.u[4] = f2bf(va[1].x); w0.u[5] = f2bf(va[1].y); w0.u[6] = f2bf(va[1].z); w0.u[7] = f2bf(va[1].w);
    w1.u[0] = f2bf(va[2].x); w1.u[1] = f2bf(va[2].y); w1.u[2] = f2bf(va[2].z); w1.u[3] = f2bf(va[2].w);
    w1.u[4] = f2bf(va[3].x); w1.u[5] = f2bf(va[3].y); w1.u[6] = f2bf(va[3].z); w1.u[7] = f2bf(va[3].w);
    const int s0 = (2 * ah) ^ ap, s1 = (2 * ah + 1) ^ ap;
    *reinterpret_cast<uint4*>(&As[buf][arow_l * 32 + s0 * 8]) = w0.qv;
    *reinterpret_cast<uint4*>(&As[buf][arow_l * 32 + s1 * 8]) = w1.qv;
  };
  auto stageW = [&](int buf, int kb) {
#pragma unroll
    for (int i2 = 0; i2 < 2; ++i2) {
      int f = i2 * 256 + tid;
      int row = f >> 2;
      int sc = ((f & 3) ^ ((row >> 1) & 3)) << 3;  // pre-swizzled source, linear dest
      gll16(Wg + (size_t)row * K + kb + sc, &Ws[buf][f * 8]);
    }
  };

  // prologue: W(0) in flight; A(0) written; A(1) in regs
  stageW(0, 0);
  loadA(0);
  writeA(0);
  loadA(1);

  for (int kt = 0; kt < KT; ++kt) {
    const int cur = kt & 1;
    __syncthreads();  // buf[cur] complete; buf[cur^1] readers done
    if (kt + 1 < KT) {
      stageW(cur ^ 1, (kt + 1) * 32);
      writeA(cur ^ 1);             // va holds A(kt+1)
    }
    if (kt + 2 < KT) loadA(kt + 2);  // issue early (T14)

    short8 af[4], wf[4];
#pragma unroll
    for (int mi = 0; mi < 4; ++mi) {
      int rw = wm * 64 + mi * 16 + lm;
      af[mi] = *reinterpret_cast<const short8*>(
          &As[cur][rw * 32 + ((rch ^ ((rw >> 1) & 3)) << 3)]);
    }
#pragma unroll
    for (int ni = 0; ni < 4; ++ni) {
      int rw = wn * 64 + ni * 16 + lm;
      wf[ni] = *reinterpret_cast<const short8*>(
          &Ws[cur][rw * 32 + ((rch ^ ((rw >> 1) & 3)) << 3)]);
    }
    __builtin_amdgcn_s_setprio(1);
#pragma unroll
    for (int mi = 0; mi < 4; ++mi)
#pragma unroll
      for (int ni = 0; ni < 4; ++ni)
        acc[mi][ni] = __builtin_amdgcn_mfma_f32_16x16x32_bf16(wf[ni], af[mi], acc[mi][ni], 0, 0, 0);
    __builtin_amdgcn_s_setprio(0);
  }

  // epilogue: thread holds C[m][n0..n0+3]; m = ..+lm, n0 = ..+rch*4
#pragma unroll
  for (int mi = 0; mi < 4; ++mi) {
    const int m = mt * 128 + wm * 64 + mi * 16 + lm;
#pragma unroll
    for (int ni = 0; ni < 4; ++ni) {
      const int n0 = nt * 128 + wn * 64 + ni * 16 + (rch << 2);
      const f32x4 bb = *reinterpret_cast<const f32x4*>(b0 + n0);
      f32x4 v = acc[mi][ni];
      union { unsigned short u[4]; uint2 qv; } o;
#pragma unroll
      for (int rr = 0; rr < 4; ++rr) o.u[rr] = f2bf(softplus_fast(v[rr] + bb[rr]));
      *reinterpret_cast<uint2*>(H0 + (size_t)m * 512 + n0) = o.qv;
    }
  }
}

// ---------------------------------------------------------------------------
// GEMM1 (+logit fusion): logits[m] += sum_n softplus(H0*W1T^T + b1)[m][n]*W2[n]
// Same 128x128 tile; both panels via global_load_lds.
// ---------------------------------------------------------------------------
__global__ __launch_bounds__(256, 3) void gemm1(const unsigned short* __restrict__ H0,
                                                const unsigned short* __restrict__ W1T,
                                                const float* __restrict__ b1,
                                                const float* __restrict__ W2,
                                                float* __restrict__ logits, int nwg) {
  constexpr int K = 512, KT = 16;
  __shared__ unsigned short As[2][128 * 32];
  __shared__ unsigned short Ws[2][128 * 32];
  const int L = xcd_swz(blockIdx.x, nwg);
  const int nt = L & 3, mt = L >> 2;
  const int tid = threadIdx.x, lane = tid & 63, wid = tid >> 6;
  const int wm = wid >> 1, wn = wid & 1, lm = lane & 15, rch = lane >> 4;

  const unsigned short* Ag = H0 + (size_t)(mt * 128) * K;
  const unsigned short* Wg = W1T + (size_t)(nt * 128) * K;

  f32x4 acc[4][4] = {};

  auto stage = [&](int buf, int kb) {
#pragma unroll
    for (int i2 = 0; i2 < 2; ++i2) {
      int f = i2 * 256 + tid;
      int row = f >> 2;
      int sc = ((f & 3) ^ ((row >> 1) & 3)) << 3;
      gll16(Ag + (size_t)row * K + kb + sc, &As[buf][f * 8]);
      gll16(Wg + (size_t)row * K + kb + sc, &Ws[buf][f * 8]);
    }
  };

  stage(0, 0);

  for (int kt = 0; kt < KT; ++kt) {
    const int cur = kt & 1;
    __syncthreads();
    if (kt + 1 < KT) stage(cur ^ 1, (kt + 1) * 32);

    short8 af[4], wf[4];
#pragma unroll
    for (int mi = 0; mi < 4; ++mi) {
      int rw = wm * 64 + mi * 16 + lm;
      af[mi] = *reinterpret_cast<const short8*>(
          &As[cur][rw * 32 + ((rch ^ ((rw >> 1) & 3)) << 3)]);
    }
#pragma unroll
    for (int ni = 0; ni < 4; ++ni) {
      int rw = wn * 64 + ni * 16 + lm;
      wf[ni] = *reinterpret_cast<const short8*>(
          &Ws[cur][rw * 32 + ((rch ^ ((rw >> 1) & 3)) << 3)]);
    }
    __builtin_amdgcn_s_setprio(1);
#pragma unroll
    for (int mi = 0; mi < 4; ++mi)
#pragma unroll
      for (int ni = 0; ni < 4; ++ni)
        acc[mi][ni] = __builtin_amdgcn_mfma_f32_16x16x32_bf16(wf[ni], af[mi], acc[mi][ni], 0, 0, 0);
    __builtin_amdgcn_s_setprio(0);
  }

  // fused epilogue: row-partials of softplus(z)*W2, one atomic per row/16 lanes
#pragma unroll
  for (int mi = 0; mi < 4; ++mi) {
    const int m = mt * 128 + wm * 64 + mi * 16 + lm;
    float part = 0.f;
#pragma unroll
    for (int ni = 0; ni < 4; ++ni) {
      const int n0 = nt * 128 + wn * 64 + ni * 16 + (rch << 2);
      const f32x4 bb = *reinterpret_cast<const f32x4*>(b1 + n0);
      const f32x4 wv = *reinterpret_cast<const f32x4*>(W2 + n0);
      f32x4 v = acc[mi][ni];
#pragma unroll
      for (int rr = 0; rr < 4; ++rr) part += softplus_fast(v[rr] + bb[rr]) * wv[rr];
    }
    part += __shfl_xor(part, 16);
    part += __shfl_xor(part, 32);
    if (lane < 16) atomicAdd(logits + m, part);
  }
}

// ---------------------------------------------------------------------------
// Per-segment softmax: one block per segment; batch sorted -> binary search.
// (b2 omitted: softmax is shift-invariant.)
// ---------------------------------------------------------------------------
__global__ __launch_bounds__(256) void segsoftmax(const float* __restrict__ logits,
                                                  const int* __restrict__ batch,
                                                  float* __restrict__ out, int N) {
  const int g = blockIdx.x;
  const int tid = threadIdx.x;
  int lo = 0, hi = N;
  while (lo < hi) { int mid = (lo + hi) >> 1; if (batch[mid] < g) lo = mid + 1; else hi = mid; }
  const int beg = lo;
  hi = N;
  while (lo < hi) { int mid = (lo + hi) >> 1; if (batch[mid] < g + 1) lo = mid + 1; else hi = mid; }
  const int end = lo;
  if (beg >= end) return;

  __shared__ float sh[4];
  float m = -INFINITY;
  for (int i = beg + tid; i < end; i += 256) m = fmaxf(m, logits[i]);
#pragma unroll
  for (int o = 32; o; o >>= 1) m = fmaxf(m, __shfl_down(m, o));
  if ((tid & 63) == 0) sh[tid >> 6] = m;
  __syncthreads();
  m = fmaxf(fmaxf(sh[0], sh[1]), fmaxf(sh[2], sh[3]));
  __syncthreads();

  float s = 0.f;
  for (int i = beg + tid; i < end; i += 256) s += expf(logits[i] - m);
#pragma unroll
  for (int o = 32; o; o >>= 1) s += __shfl_down(s, o);
  if ((tid & 63) == 0) sh[tid >> 6] = s;
  __syncthreads();
  s = sh[0] + sh[1] + sh[2] + sh[3];

  const float inv = 1.f / (s + 1e-16f);
  for (int i = beg + tid; i < end; i += 256) out[i] = expf(logits[i] - m) * inv;
}

// ---------------------------------------------------------------------------
extern "C" void kernel_launch(void* const* d_in, const int* in_sizes, int n_in,
                              void* d_out, int out_size, void* d_ws, size_t ws_size,
                              hipStream_t stream) {
  const float* x = (const float*)d_in[0];
  const int* batch = (const int*)d_in[1];
  const float* gx = (const float*)d_in[2];
  const float* W0 = (const float*)d_in[3];
  const float* b0 = (const float*)d_in[4];
  const float* W1 = (const float*)d_in[5];
  const float* b1 = (const float*)d_in[6];
  const float* W2 = (const float*)d_in[7];
  float* out = (float*)d_out;

  const int N = in_sizes[1];                 // 100000
  const int Mp = ((N + 127) / 128) * 128;    // 100096
  const int nwg = (Mp / 128) * 4;            // 3128 blocks per GEMM

  auto align256 = [](size_t v) { return (v + 255) & ~(size_t)255; };
  char* ws = (char*)d_ws;
  size_t off = 0;
  unsigned short* W0T = (unsigned short*)(ws + off); off = align256(off + (size_t)512 * 640 * 2);
  unsigned short* W1T = (unsigned short*)(ws + off); off = align256(off + (size_t)512 * 512 * 2);
  unsigned short* H0 = (unsigned short*)(ws + off);  off = align256(off + (size_t)Mp * 512 * 2);
  float* logits = (float*)(ws + off);                off = align256(off + (size_t)Mp * 4);
  (void)ws_size; (void)n_in; (void)out_size;

  const int prep_elems = 512 * 640 + 512 * 512 + Mp;
  prep<<<(prep_elems + 255) / 256, 256, 0, stream>>>(W0, W1, W0T, W1T, logits, Mp);

  gemm0<<<nwg, 256, 0, stream>>>(x, gx, W0T, b0, H0, N, nwg);
  gemm1<<<nwg, 256, 0, stream>>>(H0, W1T, b1, W2, logits, nwg);

  segsoftmax<<<NSEG, 256, 0, stream>>>(logits, batch, out, N);
}

// Round 5
// 311.861 us; speedup vs baseline: 1.2057x; 1.0103x over previous
//
#include <hip/hip_runtime.h>
#include <hip/hip_bf16.h>
#include <math.h>

// ---------------------------------------------------------------------------
// GATGNN global attention:  softmax_seg( MLP([x|glbl]) )  on MI355X (gfx950)
// R5: split pack_a0 (memory-bound) + both GEMMs in the proven structure:
//     128x128 tile, 4 waves, BK=32, global_load_lds both panels, 32KB LDS,
//     3 blocks/CU, XCD-chunked swizzle, setprio(1) around MFMA.
// ---------------------------------------------------------------------------

#define NSEG 1024

typedef __attribute__((ext_vector_type(8))) short short8;
typedef __attribute__((ext_vector_type(4))) float f32x4;

__device__ __forceinline__ unsigned short f2bf(float f) {
  __hip_bfloat16 h = __float2bfloat16(f);
  return *reinterpret_cast<unsigned short*>(&h);
}
__device__ __forceinline__ float softplus_fast(float z) {
  float t = __expf(-fabsf(z));
  return fmaxf(z, 0.f) + __logf(1.f + t);
}
__device__ __forceinline__ void gll16(const unsigned short* g, unsigned short* l) {
  __builtin_amdgcn_global_load_lds(
      (const __attribute__((address_space(1))) void*)g,
      (__attribute__((address_space(3))) void*)l, 16, 0, 0);
}
// m204 bijective XCD-chunked swizzle: each XCD owns a contiguous L-range.
__device__ __forceinline__ int xcd_swz(int bid, int nwg) {
  int q = nwg >> 3, r = nwg & 7, x = bid & 7, i = bid >> 3;
  return (x < r ? x * (q + 1) : r * (q + 1) + (x - r) * q) + i;
}

// ---------------------------------------------------------------------------
// prep: W0 [620,512] -> W0T bf16 [512,640] (K-pad 0), W1 -> W1T [512,512],
//       zero logits.
// ---------------------------------------------------------------------------
__global__ __launch_bounds__(256) void prep(const float* __restrict__ W0,
                                            const float* __restrict__ W1,
                                            unsigned short* __restrict__ W0T,
                                            unsigned short* __restrict__ W1T,
                                            float* __restrict__ logits, int Mp) {
  int t = blockIdx.x * 256 + threadIdx.x;
  if (t < 512 * 640) {
    int n = t / 640, k = t % 640;
    W0T[t] = f2bf(k < 620 ? W0[(size_t)k * 512 + n] : 0.f);
    return;
  }
  t -= 512 * 640;
  if (t < 512 * 512) {
    int n = t / 512, k = t % 512;
    W1T[t] = f2bf(W1[(size_t)k * 512 + n]);
    return;
  }
  t -= 512 * 512;
  if (t < Mp) logits[t] = 0.f;
}

// ---------------------------------------------------------------------------
// Pack A0 = [x | glbl | zeros] as bf16 [Mp, 640]; pad rows (>=N) zeroed.
// One thread per 8-elem chunk (16B store), memory-bound.
// ---------------------------------------------------------------------------
__global__ __launch_bounds__(256) void pack_a0(const float* __restrict__ x,
                                               const float* __restrict__ gx,
                                               unsigned short* __restrict__ A0,
                                               int N, int Mp) {
  int t = blockIdx.x * 256 + threadIdx.x;
  if (t >= Mp * 80) return;
  int row = t / 80, c = t % 80;
  union { unsigned short u[8]; uint4 q; } v;
  if (row >= N) {
#pragma unroll
    for (int j = 0; j < 8; ++j) v.u[j] = 0;
  } else if (c < 64) {
    const float4* p = (const float4*)(x + (size_t)row * 512 + c * 8);
    float4 a = p[0], b = p[1];
    v.u[0] = f2bf(a.x); v.u[1] = f2bf(a.y); v.u[2] = f2bf(a.z); v.u[3] = f2bf(a.w);
    v.u[4] = f2bf(b.x); v.u[5] = f2bf(b.y); v.u[6] = f2bf(b.z); v.u[7] = f2bf(b.w);
  } else {
#pragma unroll
    for (int j = 0; j < 8; ++j) {
      int col = c * 8 + j;
      float f = (col < 620) ? gx[(size_t)row * 108 + (col - 512)] : 0.f;
      v.u[j] = f2bf(f);
    }
  }
  *reinterpret_cast<uint4*>(A0 + (size_t)row * 640 + c * 8) = v.q;
}

// ---------------------------------------------------------------------------
// GEMM: Z[M,512] = A[M,K] * WT[512,K]^T + bias; 128x128 tile, BK=32, 4 waves
// (2x2), 64x64/wave, mfma(w,a) (swapped operands) so each thread holds 4
// consecutive output columns. Both panels via global_load_lds, pre-swizzled
// source (chunk c of local row r lives at slot c^((r>>1)&3) -> conflict-free
// ds_read_b128). 32KB LDS, 3 blocks/CU.
//  FUSE=false: C = bf16(softplus(Z))                       (layer 0 -> H0)
//  FUSE=true : logits[m] += sum_n softplus(Z[m,n])*W2[n]   (layers 1+2)
// ---------------------------------------------------------------------------
template <int K, bool FUSE>
__global__ __launch_bounds__(256, 3) void gemm_bf16(const unsigned short* __restrict__ A,
                                                    const unsigned short* __restrict__ WT,
                                                    const float* __restrict__ bias,
                                                    unsigned short* __restrict__ C,
                                                    const float* __restrict__ W2,
                                                    float* __restrict__ logits, int nwg) {
  constexpr int KT = K / 32;
  __shared__ unsigned short As[2][128 * 32];
  __shared__ unsigned short Ws[2][128 * 32];
  const int L = xcd_swz(blockIdx.x, nwg);
  const int nt = L & 3, mt = L >> 2;
  const int tid = threadIdx.x, lane = tid & 63, wid = tid >> 6;
  const int wm = wid >> 1, wn = wid & 1, lm = lane & 15, rch = lane >> 4;

  const unsigned short* Ag = A + (size_t)(mt * 128) * K;
  const unsigned short* Wg = WT + (size_t)(nt * 128) * K;

  f32x4 acc[4][4] = {};

  auto stage = [&](int buf, int kb) {
#pragma unroll
    for (int i2 = 0; i2 < 2; ++i2) {
      int f = i2 * 256 + tid;
      int row = f >> 2;
      int sc = ((f & 3) ^ ((row >> 1) & 3)) << 3;  // pre-swizzled source, linear dest
      gll16(Ag + (size_t)row * K + kb + sc, &As[buf][f * 8]);
      gll16(Wg + (size_t)row * K + kb + sc, &Ws[buf][f * 8]);
    }
  };

  stage(0, 0);

  for (int kt = 0; kt < KT; ++kt) {
    const int cur = kt & 1;
    __syncthreads();  // buf[cur] staged; buf[cur^1] readers done
    if (kt + 1 < KT) stage(cur ^ 1, (kt + 1) * 32);

    short8 af[4], wf[4];
#pragma unroll
    for (int mi = 0; mi < 4; ++mi) {
      int rw = wm * 64 + mi * 16 + lm;
      af[mi] = *reinterpret_cast<const short8*>(
          &As[cur][rw * 32 + ((rch ^ ((rw >> 1) & 3)) << 3)]);
    }
#pragma unroll
    for (int ni = 0; ni < 4; ++ni) {
      int rw = wn * 64 + ni * 16 + lm;
      wf[ni] = *reinterpret_cast<const short8*>(
          &Ws[cur][rw * 32 + ((rch ^ ((rw >> 1) & 3)) << 3)]);
    }
    __builtin_amdgcn_s_setprio(1);
#pragma unroll
    for (int mi = 0; mi < 4; ++mi)
#pragma unroll
      for (int ni = 0; ni < 4; ++ni)
        acc[mi][ni] = __builtin_amdgcn_mfma_f32_16x16x32_bf16(wf[ni], af[mi], acc[mi][ni], 0, 0, 0);
    __builtin_amdgcn_s_setprio(0);
  }

  // Transposed D layout: thread holds C[m][n0..n0+3]
  //   m  = mt*128 + wm*64 + mi*16 + (lane&15)
  //   n0 = nt*128 + wn*64 + ni*16 + (lane>>4)*4
#pragma unroll
  for (int mi = 0; mi < 4; ++mi) {
    const int m = mt * 128 + wm * 64 + mi * 16 + lm;
    float part = 0.f;
#pragma unroll
    for (int ni = 0; ni < 4; ++ni) {
      const int n0 = nt * 128 + wn * 64 + ni * 16 + (rch << 2);
      const f32x4 bb = *reinterpret_cast<const f32x4*>(bias + n0);
      f32x4 v = acc[mi][ni];
      if constexpr (!FUSE) {
        union { unsigned short u[4]; uint2 qv; } o;
#pragma unroll
        for (int rr = 0; rr < 4; ++rr) o.u[rr] = f2bf(softplus_fast(v[rr] + bb[rr]));
        *reinterpret_cast<uint2*>(C + (size_t)m * 512 + n0) = o.qv;
      } else {
        const f32x4 wv = *reinterpret_cast<const f32x4*>(W2 + n0);
#pragma unroll
        for (int rr = 0; rr < 4; ++rr) part += softplus_fast(v[rr] + bb[rr]) * wv[rr];
      }
    }
    if constexpr (FUSE) {
      part += __shfl_xor(part, 16);
      part += __shfl_xor(part, 32);
      if (lane < 16) atomicAdd(logits + m, part);
    }
  }
}

// ---------------------------------------------------------------------------
// Per-segment softmax: one block per segment; batch sorted -> binary search.
// (b2 omitted: softmax is shift-invariant.)
// ---------------------------------------------------------------------------
__global__ __launch_bounds__(256) void segsoftmax(const float* __restrict__ logits,
                                                  const int* __restrict__ batch,
                                                  float* __restrict__ out, int N) {
  const int g = blockIdx.x;
  const int tid = threadIdx.x;
  int lo = 0, hi = N;
  while (lo < hi) { int mid = (lo + hi) >> 1; if (batch[mid] < g) lo = mid + 1; else hi = mid; }
  const int beg = lo;
  hi = N;
  while (lo < hi) { int mid = (lo + hi) >> 1; if (batch[mid] < g + 1) lo = mid + 1; else hi = mid; }
  const int end = lo;
  if (beg >= end) return;

  __shared__ float sh[4];
  float m = -INFINITY;
  for (int i = beg + tid; i < end; i += 256) m = fmaxf(m, logits[i]);
#pragma unroll
  for (int o = 32; o; o >>= 1) m = fmaxf(m, __shfl_down(m, o));
  if ((tid & 63) == 0) sh[tid >> 6] = m;
  __syncthreads();
  m = fmaxf(fmaxf(sh[0], sh[1]), fmaxf(sh[2], sh[3]));
  __syncthreads();

  float s = 0.f;
  for (int i = beg + tid; i < end; i += 256) s += expf(logits[i] - m);
#pragma unroll
  for (int o = 32; o; o >>= 1) s += __shfl_down(s, o);
  if ((tid & 63) == 0) sh[tid >> 6] = s;
  __syncthreads();
  s = sh[0] + sh[1] + sh[2] + sh[3];

  const float inv = 1.f / (s + 1e-16f);
  for (int i = beg + tid; i < end; i += 256) out[i] = expf(logits[i] - m) * inv;
}

// ---------------------------------------------------------------------------
extern "C" void kernel_launch(void* const* d_in, const int* in_sizes, int n_in,
                              void* d_out, int out_size, void* d_ws, size_t ws_size,
                              hipStream_t stream) {
  const float* x = (const float*)d_in[0];
  const int* batch = (const int*)d_in[1];
  const float* gx = (const float*)d_in[2];
  const float* W0 = (const float*)d_in[3];
  const float* b0 = (const float*)d_in[4];
  const float* W1 = (const float*)d_in[5];
  const float* b1 = (const float*)d_in[6];
  const float* W2 = (const float*)d_in[7];
  float* out = (float*)d_out;

  const int N = in_sizes[1];                 // 100000
  const int Mp = ((N + 127) / 128) * 128;    // 100096
  const int nwg = (Mp / 128) * 4;            // 3128 blocks per GEMM (3128%8==0)

  auto align256 = [](size_t v) { return (v + 255) & ~(size_t)255; };
  char* ws = (char*)d_ws;
  size_t off = 0;
  unsigned short* A0 = (unsigned short*)(ws + off);  off = align256(off + (size_t)Mp * 640 * 2);
  unsigned short* W0T = (unsigned short*)(ws + off); off = align256(off + (size_t)512 * 640 * 2);
  unsigned short* W1T = (unsigned short*)(ws + off); off = align256(off + (size_t)512 * 512 * 2);
  unsigned short* H0 = (unsigned short*)(ws + off);  off = align256(off + (size_t)Mp * 512 * 2);
  float* logits = (float*)(ws + off);                off = align256(off + (size_t)Mp * 4);
  (void)ws_size; (void)n_in; (void)out_size;

  const int prep_elems = 512 * 640 + 512 * 512 + Mp;
  prep<<<(prep_elems + 255) / 256, 256, 0, stream>>>(W0, W1, W0T, W1T, logits, Mp);
  pack_a0<<<(Mp * 80 + 255) / 256, 256, 0, stream>>>(x, gx, A0, N, Mp);

  gemm_bf16<640, false><<<nwg, 256, 0, stream>>>(A0, W0T, b0, H0, nullptr, nullptr, nwg);
  gemm_bf16<512, true><<<nwg, 256, 0, stream>>>(H0, W1T, b1, nullptr, W2, logits, nwg);

  segsoftmax<<<NSEG, 256, 0, stream>>>(logits, batch, out, N);
}

// Round 6
// 301.868 us; speedup vs baseline: 1.2456x; 1.0331x over previous
//
#include <hip/hip_runtime.h>
#include <hip/hip_bf16.h>
#include <math.h>

// ---------------------------------------------------------------------------
// GATGNN global attention:  softmax_seg( MLP([x|glbl]) )  on MI355X (gfx950)
// R6: 4 blocks/CU (launch_bounds(256,4)), A split into pow2-stride panels
//     X16[Mp,512] + G16[Mp,128]. Otherwise the proven 128x128/BK=32 loop.
// ---------------------------------------------------------------------------

#define NSEG 1024

typedef __attribute__((ext_vector_type(8))) short short8;
typedef __attribute__((ext_vector_type(4))) float f32x4;

__device__ __forceinline__ unsigned short f2bf(float f) {
  __hip_bfloat16 h = __float2bfloat16(f);
  return *reinterpret_cast<unsigned short*>(&h);
}
__device__ __forceinline__ float softplus_fast(float z) {
  float t = __expf(-fabsf(z));
  return fmaxf(z, 0.f) + __logf(1.f + t);
}
__device__ __forceinline__ void gll16(const unsigned short* g, unsigned short* l) {
  __builtin_amdgcn_global_load_lds(
      (const __attribute__((address_space(1))) void*)g,
      (__attribute__((address_space(3))) void*)l, 16, 0, 0);
}
// m204 bijective XCD-chunked swizzle: each XCD owns a contiguous L-range.
__device__ __forceinline__ int xcd_swz(int bid, int nwg) {
  int q = nwg >> 3, r = nwg & 7, x = bid & 7, i = bid >> 3;
  return (x < r ? x * (q + 1) : r * (q + 1) + (x - r) * q) + i;
}

// ---------------------------------------------------------------------------
// prep: W0 [620,512] -> W0T bf16 [512,640] (K-pad 0), W1 -> W1T [512,512],
//       zero logits.
// ---------------------------------------------------------------------------
__global__ __launch_bounds__(256) void prep(const float* __restrict__ W0,
                                            const float* __restrict__ W1,
                                            unsigned short* __restrict__ W0T,
                                            unsigned short* __restrict__ W1T,
                                            float* __restrict__ logits, int Mp) {
  int t = blockIdx.x * 256 + threadIdx.x;
  if (t < 512 * 640) {
    int n = t / 640, k = t % 640;
    W0T[t] = f2bf(k < 620 ? W0[(size_t)k * 512 + n] : 0.f);
    return;
  }
  t -= 512 * 640;
  if (t < 512 * 512) {
    int n = t / 512, k = t % 512;
    W1T[t] = f2bf(W1[(size_t)k * 512 + n]);
    return;
  }
  t -= 512 * 512;
  if (t < Mp) logits[t] = 0.f;
}

// ---------------------------------------------------------------------------
// pack: x [N,512] f32 -> X16 [Mp,512] bf16 ; gx [N,108] f32 -> G16 [Mp,128]
// bf16 (cols 108..127 zero). Pad rows (>=N) zeroed. 16B stores.
// ---------------------------------------------------------------------------
__global__ __launch_bounds__(256) void pack(const float* __restrict__ x,
                                            const float* __restrict__ gx,
                                            unsigned short* __restrict__ X16,
                                            unsigned short* __restrict__ G16,
                                            int N, int Mp) {
  int t = blockIdx.x * 256 + threadIdx.x;
  union { unsigned short u[8]; uint4 q; } v;
  if (t < Mp * 64) {
    int row = t >> 6, c = t & 63;
    if (row >= N) {
#pragma unroll
      for (int j = 0; j < 8; ++j) v.u[j] = 0;
    } else {
      const float4* p = (const float4*)(x + (size_t)row * 512 + c * 8);
      float4 a = p[0], b = p[1];
      v.u[0] = f2bf(a.x); v.u[1] = f2bf(a.y); v.u[2] = f2bf(a.z); v.u[3] = f2bf(a.w);
      v.u[4] = f2bf(b.x); v.u[5] = f2bf(b.y); v.u[6] = f2bf(b.z); v.u[7] = f2bf(b.w);
    }
    *reinterpret_cast<uint4*>(X16 + (size_t)row * 512 + c * 8) = v.q;
    return;
  }
  t -= Mp * 64;
  if (t < Mp * 16) {
    int row = t >> 4, c = t & 15;
#pragma unroll
    for (int j = 0; j < 8; ++j) {
      int col = c * 8 + j;
      v.u[j] = (row < N && col < 108) ? f2bf(gx[(size_t)row * 108 + col]) : 0;
    }
    *reinterpret_cast<uint4*>(G16 + (size_t)row * 128 + c * 8) = v.q;
  }
}

// ---------------------------------------------------------------------------
// GEMM: Z[M,512] = A[M,K] * WT[512,K]^T + bias; 128x128 tile, BK=32, 4 waves
// (2x2), 64x64/wave, mfma(w,a) (swapped operands) so each thread holds 4
// consecutive output columns. Both panels via global_load_lds, pre-swizzled
// source (chunk c of local row r -> slot c^((r>>1)&3), conflict-free
// ds_read_b128). 32KB LDS, 4 blocks/CU.
//  SPLITA: A = [A1 (stride 512) | A2 (stride 128)], boundary at k=512.
//  FUSE=false: C = bf16(softplus(Z))                       (layer 0 -> H0)
//  FUSE=true : logits[m] += sum_n softplus(Z[m,n])*W2[n]   (layers 1+2)
// ---------------------------------------------------------------------------
template <int K, bool SPLITA, bool FUSE>
__global__ __launch_bounds__(256, 4) void gemm_bf16(const unsigned short* __restrict__ A1,
                                                    const unsigned short* __restrict__ A2,
                                                    const unsigned short* __restrict__ WT,
                                                    const float* __restrict__ bias,
                                                    unsigned short* __restrict__ C,
                                                    const float* __restrict__ W2,
                                                    float* __restrict__ logits, int nwg) {
  constexpr int KT = K / 32;
  __shared__ unsigned short As[2][128 * 32];
  __shared__ unsigned short Ws[2][128 * 32];
  const int L = xcd_swz(blockIdx.x, nwg);
  const int nt = L & 3, mt = L >> 2;
  const int tid = threadIdx.x, lane = tid & 63, wid = tid >> 6;
  const int wm = wid >> 1, wn = wid & 1, lm = lane & 15, rch = lane >> 4;

  const unsigned short* Ag = A1 + (size_t)(mt * 128) * 512;
  const unsigned short* A2g = SPLITA ? A2 + (size_t)(mt * 128) * 128 : nullptr;
  const unsigned short* Wg = WT + (size_t)(nt * 128) * K;

  f32x4 acc[4][4] = {};

  auto stage = [&](int buf, int kb) {
#pragma unroll
    for (int i2 = 0; i2 < 2; ++i2) {
      int f = i2 * 256 + tid;
      int row = f >> 2;
      int sc = ((f & 3) ^ ((row >> 1) & 3)) << 3;  // pre-swizzled source, linear dest
      if constexpr (SPLITA) {
        if (kb < 512) gll16(Ag + (size_t)row * 512 + kb + sc, &As[buf][f * 8]);
        else          gll16(A2g + (size_t)row * 128 + (kb - 512) + sc, &As[buf][f * 8]);
      } else {
        gll16(Ag + (size_t)row * 512 + kb + sc, &As[buf][f * 8]);
      }
      gll16(Wg + (size_t)row * K + kb + sc, &Ws[buf][f * 8]);
    }
  };

  stage(0, 0);

  for (int kt = 0; kt < KT; ++kt) {
    const int cur = kt & 1;
    __syncthreads();  // buf[cur] staged; buf[cur^1] readers done
    if (kt + 1 < KT) stage(cur ^ 1, (kt + 1) * 32);

    short8 af[4], wf[4];
#pragma unroll
    for (int mi = 0; mi < 4; ++mi) {
      int rw = wm * 64 + mi * 16 + lm;
      af[mi] = *reinterpret_cast<const short8*>(
          &As[cur][rw * 32 + ((rch ^ ((rw >> 1) & 3)) << 3)]);
    }
#pragma unroll
    for (int ni = 0; ni < 4; ++ni) {
      int rw = wn * 64 + ni * 16 + lm;
      wf[ni] = *reinterpret_cast<const short8*>(
          &Ws[cur][rw * 32 + ((rch ^ ((rw >> 1) & 3)) << 3)]);
    }
    __builtin_amdgcn_s_setprio(1);
#pragma unroll
    for (int mi = 0; mi < 4; ++mi)
#pragma unroll
      for (int ni = 0; ni < 4; ++ni)
        acc[mi][ni] = __builtin_amdgcn_mfma_f32_16x16x32_bf16(wf[ni], af[mi], acc[mi][ni], 0, 0, 0);
    __builtin_amdgcn_s_setprio(0);
  }

  // Transposed D layout: thread holds C[m][n0..n0+3]
#pragma unroll
  for (int mi = 0; mi < 4; ++mi) {
    const int m = mt * 128 + wm * 64 + mi * 16 + lm;
    float part = 0.f;
#pragma unroll
    for (int ni = 0; ni < 4; ++ni) {
      const int n0 = nt * 128 + wn * 64 + ni * 16 + (rch << 2);
      const f32x4 bb = *reinterpret_cast<const f32x4*>(bias + n0);
      f32x4 v = acc[mi][ni];
      if constexpr (!FUSE) {
        union { unsigned short u[4]; uint2 qv; } o;
#pragma unroll
        for (int rr = 0; rr < 4; ++rr) o.u[rr] = f2bf(softplus_fast(v[rr] + bb[rr]));
        *reinterpret_cast<uint2*>(C + (size_t)m * 512 + n0) = o.qv;
      } else {
        const f32x4 wv = *reinterpret_cast<const f32x4*>(W2 + n0);
#pragma unroll
        for (int rr = 0; rr < 4; ++rr) part += softplus_fast(v[rr] + bb[rr]) * wv[rr];
      }
    }
    if constexpr (FUSE) {
      part += __shfl_xor(part, 16);
      part += __shfl_xor(part, 32);
      if (lane < 16) atomicAdd(logits + m, part);
    }
  }
}

// ---------------------------------------------------------------------------
// Per-segment softmax: one block per segment; batch sorted -> binary search.
// (b2 omitted: softmax is shift-invariant.)
// ---------------------------------------------------------------------------
__global__ __launch_bounds__(256) void segsoftmax(const float* __restrict__ logits,
                                                  const int* __restrict__ batch,
                                                  float* __restrict__ out, int N) {
  const int g = blockIdx.x;
  const int tid = threadIdx.x;
  int lo = 0, hi = N;
  while (lo < hi) { int mid = (lo + hi) >> 1; if (batch[mid] < g) lo = mid + 1; else hi = mid; }
  const int beg = lo;
  hi = N;
  while (lo < hi) { int mid = (lo + hi) >> 1; if (batch[mid] < g + 1) lo = mid + 1; else hi = mid; }
  const int end = lo;
  if (beg >= end) return;

  __shared__ float sh[4];
  float m = -INFINITY;
  for (int i = beg + tid; i < end; i += 256) m = fmaxf(m, logits[i]);
#pragma unroll
  for (int o = 32; o; o >>= 1) m = fmaxf(m, __shfl_down(m, o));
  if ((tid & 63) == 0) sh[tid >> 6] = m;
  __syncthreads();
  m = fmaxf(fmaxf(sh[0], sh[1]), fmaxf(sh[2], sh[3]));
  __syncthreads();

  float s = 0.f;
  for (int i = beg + tid; i < end; i += 256) s += expf(logits[i] - m);
#pragma unroll
  for (int o = 32; o; o >>= 1) s += __shfl_down(s, o);
  if ((tid & 63) == 0) sh[tid >> 6] = s;
  __syncthreads();
  s = sh[0] + sh[1] + sh[2] + sh[3];

  const float inv = 1.f / (s + 1e-16f);
  for (int i = beg + tid; i < end; i += 256) out[i] = expf(logits[i] - m) * inv;
}

// ---------------------------------------------------------------------------
extern "C" void kernel_launch(void* const* d_in, const int* in_sizes, int n_in,
                              void* d_out, int out_size, void* d_ws, size_t ws_size,
                              hipStream_t stream) {
  const float* x = (const float*)d_in[0];
  const int* batch = (const int*)d_in[1];
  const float* gx = (const float*)d_in[2];
  const float* W0 = (const float*)d_in[3];
  const float* b0 = (const float*)d_in[4];
  const float* W1 = (const float*)d_in[5];
  const float* b1 = (const float*)d_in[6];
  const float* W2 = (const float*)d_in[7];
  float* out = (float*)d_out;

  const int N = in_sizes[1];                 // 100000
  const int Mp = ((N + 127) / 128) * 128;    // 100096
  const int nwg = (Mp / 128) * 4;            // 3128 blocks per GEMM (3128%8==0)

  auto align256 = [](size_t v) { return (v + 255) & ~(size_t)255; };
  char* ws = (char*)d_ws;
  size_t off = 0;
  unsigned short* X16 = (unsigned short*)(ws + off); off = align256(off + (size_t)Mp * 512 * 2);
  unsigned short* G16 = (unsigned short*)(ws + off); off = align256(off + (size_t)Mp * 128 * 2);
  unsigned short* W0T = (unsigned short*)(ws + off); off = align256(off + (size_t)512 * 640 * 2);
  unsigned short* W1T = (unsigned short*)(ws + off); off = align256(off + (size_t)512 * 512 * 2);
  unsigned short* H0 = (unsigned short*)(ws + off);  off = align256(off + (size_t)Mp * 512 * 2);
  float* logits = (float*)(ws + off);                off = align256(off + (size_t)Mp * 4);
  (void)ws_size; (void)n_in; (void)out_size;

  const int prep_elems = 512 * 640 + 512 * 512 + Mp;
  prep<<<(prep_elems + 255) / 256, 256, 0, stream>>>(W0, W1, W0T, W1T, logits, Mp);
  pack<<<(Mp * 80 + 255) / 256, 256, 0, stream>>>(x, gx, X16, G16, N, Mp);

  gemm_bf16<640, true, false><<<nwg, 256, 0, stream>>>(X16, G16, W0T, b0, H0, nullptr, nullptr, nwg);
  gemm_bf16<512, false, true><<<nwg, 256, 0, stream>>>(H0, nullptr, W1T, b1, nullptr, W2, logits, nwg);

  segsoftmax<<<NSEG, 256, 0, stream>>>(logits, batch, out, N);
}